// Round 3
// baseline (34804.614 us; speedup 1.0000x reference)
//
#include <hip/hip_runtime.h>

#define TPB   512
#define NBLK  256
#define UNITS 32
#define HID   1024

static_assert(NBLK * TPB == 131072, "grid must cover batch exactly");

__global__ __launch_bounds__(TPB, 2)
void hopfield_rk4_f32(const float* __restrict__ x,  const float* __restrict__ W1,
                      const float* __restrict__ b1, const float* __restrict__ W2,
                      const float* __restrict__ b2, float* __restrict__ out) {
    // fp32 W1^T [j][u] in LDS (128 KB) — rows are 128 B, 16B-aligned, read as
    // float4 broadcasts (all lanes same address -> conflict-free).
    // W2 stays in global (L2-resident, uniform-address reads).
    __shared__ __align__(16) float sW1T[HID * UNITS];
    __shared__ float sb1[HID];

    const int tid = threadIdx.x;
    #pragma unroll 1
    for (int idx = tid; idx < UNITS * HID; idx += TPB) {
        int u = idx >> 10, j = idx & (HID - 1);
        sW1T[j * UNITS + u] = W1[idx];          // transpose [32][1024] -> [j][u]
    }
    #pragma unroll 1
    for (int j = tid; j < HID; j += TPB) sb1[j] = b1[j];
    __syncthreads();

    const long sample = (long)blockIdx.x * TPB + tid;
    float zb[UNITS];
    {
        const float4* xr = (const float4*)(x + sample * UNITS);
        #pragma unroll
        for (int q = 0; q < 8; ++q) {
            float4 v = xr[q];
            zb[4*q+0] = v.x; zb[4*q+1] = v.y; zb[4*q+2] = v.z; zb[4*q+3] = v.w;
        }
    }

    const float dt = 0.1f;
    const float4* W2r = (const float4*)W2;     // row j = W2r[j*8 .. j*8+7]
    const float4* b2r = (const float4*)b2;

    #pragma unroll 1
    for (int step = 0; step < 10; ++step) {
        float acc[UNITS], zc[UNITS];
        #pragma unroll
        for (int u = 0; u < UNITS; ++u) { acc[u] = 0.f; zc[u] = zb[u]; }

        #pragma unroll 1
        for (int sub = 0; sub < 4; ++sub) {
            float yg[UNITS];
            #pragma unroll
            for (int u = 0; u < UNITS; ++u) yg[u] = 0.f;

            // ---------- forward: h_j = b1_j + zc.W1col_j ; y += relu(h_j)*W2row_j ----------
            #pragma unroll 1
            for (int j = 0; j < HID; ++j) {
                const float4* w1r = (const float4*)(sW1T + j * UNITS);
                float4 wr[8];
                #pragma unroll
                for (int q = 0; q < 8; ++q) wr[q] = w1r[q];

                float p0 = sb1[j], p1 = 0.f, p2 = 0.f, p3 = 0.f;
                #pragma unroll
                for (int q = 0; q < 8; ++q) {
                    p0 = fmaf(zc[4*q+0], wr[q].x, p0);
                    p1 = fmaf(zc[4*q+1], wr[q].y, p1);
                    p2 = fmaf(zc[4*q+2], wr[q].z, p2);
                    p3 = fmaf(zc[4*q+3], wr[q].w, p3);
                }
                float h = (p0 + p1) + (p2 + p3);
                float r = fmaxf(h, 0.f);

                #pragma unroll
                for (int q = 0; q < 8; ++q) {
                    float4 wv = W2r[j * 8 + q];          // uniform address
                    yg[4*q+0] = fmaf(r, wv.x, yg[4*q+0]);
                    yg[4*q+1] = fmaf(r, wv.y, yg[4*q+1]);
                    yg[4*q+2] = fmaf(r, wv.z, yg[4*q+2]);
                    yg[4*q+3] = fmaf(r, wv.w, yg[4*q+3]);
                }
            }

            // ---------- g = 8*y/||y|| (in place) ----------
            #pragma unroll
            for (int q = 0; q < 8; ++q) {
                float4 bv = b2r[q];
                yg[4*q+0] += bv.x; yg[4*q+1] += bv.y;
                yg[4*q+2] += bv.z; yg[4*q+3] += bv.w;
            }
            float n0 = 0.f, n1 = 0.f, n2 = 0.f, n3 = 0.f;
            #pragma unroll
            for (int u = 0; u < UNITS; u += 4) {
                n0 = fmaf(yg[u+0], yg[u+0], n0); n1 = fmaf(yg[u+1], yg[u+1], n1);
                n2 = fmaf(yg[u+2], yg[u+2], n2); n3 = fmaf(yg[u+3], yg[u+3], n3);
            }
            float s8 = 8.0f * rsqrtf((n0 + n1) + (n2 + n3));
            #pragma unroll
            for (int u = 0; u < UNITS; ++u) yg[u] *= s8;

            float k[UNITS];
            #pragma unroll
            for (int u = 0; u < UNITS; ++u) k[u] = 0.f;

            // ---------- backward: recompute h_j; gr_j = g.W2row_j ; k -= relu'(h_j)*gr_j*W1col_j ----------
            #pragma unroll 1
            for (int j = 0; j < HID; ++j) {
                const float4* w1r = (const float4*)(sW1T + j * UNITS);
                float4 wr[8];
                #pragma unroll
                for (int q = 0; q < 8; ++q) wr[q] = w1r[q];

                float p0 = sb1[j], p1 = 0.f, p2 = 0.f, p3 = 0.f;
                float q0 = 0.f, q1 = 0.f, q2 = 0.f, q3 = 0.f;
                #pragma unroll
                for (int q = 0; q < 8; ++q) {
                    float4 wv = W2r[j * 8 + q];          // uniform address
                    p0 = fmaf(zc[4*q+0], wr[q].x, p0);
                    p1 = fmaf(zc[4*q+1], wr[q].y, p1);
                    p2 = fmaf(zc[4*q+2], wr[q].z, p2);
                    p3 = fmaf(zc[4*q+3], wr[q].w, p3);
                    q0 = fmaf(yg[4*q+0], wv.x, q0);
                    q1 = fmaf(yg[4*q+1], wv.y, q1);
                    q2 = fmaf(yg[4*q+2], wv.z, q2);
                    q3 = fmaf(yg[4*q+3], wv.w, q3);
                }
                float h  = (p0 + p1) + (p2 + p3);
                float gr = (q0 + q1) + (q2 + q3);
                float gh = (h > 0.f) ? -gr : 0.f;   // pvf = -grad; relu' at 0 = 0

                #pragma unroll
                for (int q = 0; q < 8; ++q) {
                    k[4*q+0] = fmaf(gh, wr[q].x, k[4*q+0]);
                    k[4*q+1] = fmaf(gh, wr[q].y, k[4*q+1]);
                    k[4*q+2] = fmaf(gh, wr[q].z, k[4*q+2]);
                    k[4*q+3] = fmaf(gh, wr[q].w, k[4*q+3]);
                }
            }

            // ---------- RK4 bookkeeping ----------
            float aw = (sub == 0 || sub == 3) ? 1.f : 2.f;
            #pragma unroll
            for (int u = 0; u < UNITS; ++u) acc[u] += aw * k[u];
            if (sub < 3) {
                float cw = (sub == 2) ? dt : 0.5f * dt;
                #pragma unroll
                for (int u = 0; u < UNITS; ++u) zc[u] = fmaf(cw, k[u], zb[u]);
            }
        }

        #pragma unroll
        for (int u = 0; u < UNITS; ++u) zb[u] = fmaf(dt * (1.f / 6.f), acc[u], zb[u]);
    }

    float4* orow = (float4*)(out + sample * UNITS);
    #pragma unroll
    for (int q = 0; q < 8; ++q) {
        float4 v;
        v.x = zb[4*q+0]; v.y = zb[4*q+1]; v.z = zb[4*q+2]; v.w = zb[4*q+3];
        orow[q] = v;
    }
}

extern "C" void kernel_launch(void* const* d_in, const int* in_sizes, int n_in,
                              void* d_out, int out_size, void* d_ws, size_t ws_size,
                              hipStream_t stream) {
    const float* x  = (const float*)d_in[0];
    const float* W1 = (const float*)d_in[1];
    const float* b1 = (const float*)d_in[2];
    const float* W2 = (const float*)d_in[3];
    const float* b2 = (const float*)d_in[4];
    float* out = (float*)d_out;
    hipLaunchKernelGGL(hopfield_rk4_f32, dim3(NBLK), dim3(TPB), 0, stream,
                       x, W1, b1, W2, b2, out);
}